// Round 9
// baseline (193.833 us; speedup 1.0000x reference)
//
#include <hip/hip_runtime.h>
#include <hip/hip_bf16.h>

typedef __bf16 bf16x8 __attribute__((ext_vector_type(8)));
typedef float  f32x16 __attribute__((ext_vector_type(16)));
typedef float  f32x4  __attribute__((ext_vector_type(4)));
typedef float  f32x2  __attribute__((ext_vector_type(2)));

static __device__ __forceinline__ f32x16 mfma32(bf16x8 a, bf16x8 b, f32x16 c) {
    return __builtin_amdgcn_mfma_f32_32x32x16_bf16(a, b, c, 0, 0, 0);
}

// async global->LDS, 16B per lane; LDS dest = wave-uniform base + lane*16 (HW)
static __device__ __forceinline__ void gl_lds16(const void* g, void* l) {
    __builtin_amdgcn_global_load_lds(
        (const __attribute__((address_space(1))) unsigned int*)g,
        (__attribute__((address_space(3))) unsigned int*)l,
        16, 0, 0);
}

// gelu-tanh via sigmoid with log2e folded in:
// gelu(h) = h / (1 + exp2(-h*(C1 + C2*h^2)))
#define GELU_C1 2.30220820f
#define GELU_C2 0.10294324f

// gelu+gate on 8 consecutive accumulator elems, written in f32x2 packed form
// so clang emits v_pk_mul_f32 / v_pk_fma_f32 / v_pk_add_f32. Elementwise math
// identical to the scalar version used in rounds 2-8 (same fma/mul order).
static __device__ __forceinline__ bf16x8 gelu8p(f32x16 a, int base, f32x2 gv2) {
    const f32x2 c2  = {-GELU_C2, -GELU_C2};
    const f32x2 c1  = {-GELU_C1, -GELU_C1};
    const f32x2 one = {1.f, 1.f};
    bf16x8 r;
    #pragma unroll
    for (int p = 0; p < 4; ++p) {
        f32x2 hh; hh[0] = a[base + 2 * p]; hh[1] = a[base + 2 * p + 1];
        f32x2 tt = hh * hh;              // pk_mul
        f32x2 pp = tt * c2 + c1;         // pk_fma (contracted)
        f32x2 mm = hh * pp;              // pk_mul
        f32x2 ee;
        ee[0] = __builtin_amdgcn_exp2f(mm[0]);
        ee[1] = __builtin_amdgcn_exp2f(mm[1]);
        f32x2 dd = one + ee;             // pk_add
        f32x2 qq;
        qq[0] = __builtin_amdgcn_rcpf(dd[0]);
        qq[1] = __builtin_amdgcn_rcpf(dd[1]);
        f32x2 gg = (hh * qq) * gv2;      // 2x pk_mul
        r[2 * p]     = (__bf16)gg[0];
        r[2 * p + 1] = (__bf16)gg[1];
    }
    return r;
}

// ---------------------------------------------------------------------------
// Pack kernel: W1p (K=128), W2p (sigma-permuted, [e][kq][ot] order), be1p
// (f32 layer-1 bias in MFMA D-fragment order), router weights fp64.
// ---------------------------------------------------------------------------
__global__ __launch_bounds__(256) void pack_kernel(
    const float* __restrict__ We1, const float* __restrict__ be1,
    const float* __restrict__ Ws1, const float* __restrict__ bs1,
    const float* __restrict__ We2, const float* __restrict__ Ws2,
    const float* __restrict__ Wr1, const float* __restrict__ br1,
    const float* __restrict__ Wr2, const float* __restrict__ br2,
    __bf16* __restrict__ w1p, __bf16* __restrict__ w2p,
    float* __restrict__ be1p,
    double* __restrict__ wr1d, double* __restrict__ br1d,
    double* __restrict__ wr2d, double* __restrict__ br2d)
{
    int tid = blockIdx.x * 256 + threadIdx.x;
    if (tid < 20480) {
        // W1p: [e][nt][ks][64 lanes][8]; n = nt*32+(l&31), k = ks*16+(l>>5)*8+j
        int l  = tid & 63;
        int ks = (tid >> 6) & 7;
        int nt = (tid >> 9) & 3;
        int e  = tid >> 11;
        const float* src = (e < 8) ? (We1 + e * 16384) : (Ws1 + (e - 8) * 16384);
        int n  = nt * 32 + (l & 31);
        int kb = ks * 16 + (l >> 5) * 8;
        bf16x8 v;
        #pragma unroll
        for (int j = 0; j < 8; ++j) v[j] = (__bf16)src[(kb + j) * 128 + n];
        *(bf16x8*)(w1p + (size_t)tid * 8) = v;
    } else if (tid < 40960) {
        // W2p: [e][kq][ot][64 lanes][8]; sigma-permuted k within each kq group
        int t2 = tid - 20480;
        int l  = t2 & 63;
        int ot = (t2 >> 6) & 3;
        int kq = (t2 >> 8) & 7;
        int e  = t2 >> 11;
        const float* src = (e < 8) ? (We2 + e * 16384) : (Ws2 + (e - 8) * 16384);
        int o  = 32 * ot + (l & 31);
        int lh = l >> 5;
        bf16x8 v;
        #pragma unroll
        for (int j = 0; j < 8; ++j) {
            int hid = 16 * kq + 8 * (j >> 2) + 4 * lh + (j & 3);
            v[j] = (__bf16)src[hid * 128 + o];
        }
        *(bf16x8*)(w2p + (size_t)t2 * 8) = v;
    } else if (tid < 42240) {
        // be1p: [e][nt][hi][16 r] with n = 32nt + (r&3)+8*(r>>2)+4*hi (f32 exact)
        int i  = tid - 40960;
        int r  = i & 15;
        int h2 = (i >> 4) & 1;
        int nt = (i >> 5) & 3;
        int e  = i >> 7;
        int n  = 32 * nt + (r & 3) + 8 * (r >> 2) + 4 * h2;
        be1p[i] = (e < 8) ? be1[e * 128 + n] : bs1[(e - 8) * 128 + n];
    } else if (tid < 44288) {
        int i = tid - 42240;            // 0..2047: Wr1 [128][16]
        wr1d[i] = (double)Wr1[i];
    } else if (tid < 44416) {
        int i = tid - 44288;            // 0..127: Wr2 [16][8]
        wr2d[i] = (double)Wr2[i];
    } else if (tid < 44432) {
        int i = tid - 44416;            // 0..15
        br1d[i] = (double)br1[i];
    } else if (tid < 44440) {
        int i = tid - 44432;            // 0..7
        br2d[i] = (double)br2[i];
    }
}

// ---------------------------------------------------------------------------
// Router kernel (fp64, decision-exact) — round-1 version verbatim (~17.6 us).
// Gate decisions bit-identical to all prior rounds.
// ---------------------------------------------------------------------------
__global__ __launch_bounds__(256) void router_kernel(
    const float* __restrict__ x,
    const double* __restrict__ wr1d, const double* __restrict__ br1d,
    const double* __restrict__ wr2d, const double* __restrict__ br2d,
    float* __restrict__ gates)
{
    __shared__ __align__(16) char lds[41472];
    float*  xs  = (float*)lds;                 // 64 rows * 130 f32 = 33280 B
    double* rfs = (double*)(lds + 33280);      // 64*16*8 = 8192 B

    const int t    = threadIdx.x;
    const int tok0 = blockIdx.x * 64;

    // stage x fp32 (stride 130 to dodge bank conflicts)
    #pragma unroll
    for (int i = 0; i < 8; ++i) {
        int cid = i * 256 + t;       // 4-float chunk id, 0..2047
        int m = cid >> 5;            // token 0..63
        int c = cid & 31;            // chunk within row
        f32x4 v = *(const f32x4*)(x + (size_t)(tok0 + m) * 128 + c * 4);
        f32x2 s0, s1;
        s0[0] = v[0]; s0[1] = v[1]; s1[0] = v[2]; s1[1] = v[3];
        *(f32x2*)(xs + m * 130 + c * 4)     = s0;
        *(f32x2*)(xs + m * 130 + c * 4 + 2) = s1;
    }
    __syncthreads();

    // ---- router layer 1 (fp64): thread (tok=t&63, rq=(t>>6)*4) -> 4 rf ----
    {
        const int tok = t & 63;
        const int rq  = (t >> 6) * 4;
        const int rqs = __builtin_amdgcn_readfirstlane(rq);  // force s_loads
        double rf4[4];
        #pragma unroll
        for (int j = 0; j < 4; ++j) rf4[j] = br1d[rqs + j];
        const float* xr = xs + tok * 130;
        #pragma unroll 4
        for (int c = 0; c < 64; ++c) {
            f32x2 xv2 = *(const f32x2*)(xr + c * 2);
            #pragma unroll
            for (int q = 0; q < 2; ++q) {
                double xv = (double)xv2[q];
                int k = c * 2 + q;
                #pragma unroll
                for (int j = 0; j < 4; ++j)
                    rf4[j] = fma(xv, wr1d[k * 16 + rqs + j], rf4[j]);
            }
        }
        #pragma unroll
        for (int j = 0; j < 4; ++j)
            rfs[tok * 16 + rq + j] = rf4[j] > 0.0 ? rf4[j] : 0.0;
    }
    __syncthreads();

    // ---- router layer 2 + softmax + div-free mask (fp64), 1 thr/token ----
    if (t < 64) {
        double lg[8];
        #pragma unroll
        for (int j = 0; j < 8; ++j) lg[j] = br2d[j];
        #pragma unroll
        for (int r = 0; r < 16; ++r) {
            double rv = rfs[t * 16 + r];
            #pragma unroll
            for (int j = 0; j < 8; ++j)
                lg[j] = fma(rv, wr2d[r * 8 + j], lg[j]);
        }
        double mx = lg[0];
        #pragma unroll
        for (int j = 1; j < 8; ++j) mx = lg[j] > mx ? lg[j] : mx;
        double ex[8]; double s = 0.0;
        #pragma unroll
        for (int j = 0; j < 8; ++j) { ex[j] = exp(lg[j] - mx); s += ex[j]; }
        double ms = 0.0;
        bool mk[8];
        #pragma unroll
        for (int j = 0; j < 8; ++j) {
            mk[j] = (8.0 * ex[j] > s);
            ms += mk[j] ? ex[j] : 0.0;
        }
        double inv = 1.0 / (ms + s * 1e-8);
        f32x4 o0, o1;
        #pragma unroll
        for (int j = 0; j < 4; ++j) {
            o0[j] = mk[j]     ? (float)(ex[j] * inv)     : 0.f;
            o1[j] = mk[4 + j] ? (float)(ex[4 + j] * inv) : 0.f;
        }
        *(f32x4*)(gates + (size_t)(tok0 + t) * 8)     = o0;
        *(f32x4*)(gates + (size_t)(tok0 + t) * 8 + 4) = o1;
    }
}

// ---------------------------------------------------------------------------
// Fused expert kernel v8: phase-split LDS ping-pong + 2 independent blocks/CU.
// Per expert: G1 phase {fill Q<-W2(e); GEMM1 from P; packed-gelu -> H regs},
// G2 phase {fill P<-W1(e+1); GEMM2 from Q}. Every fill is issued at a phase
// top and drained at its bottom (vmcnt(0)+barrier, v5's proven idiom) ->
// never naked. 64 KB/block -> two independent 256-thr blocks per CU
// (2 waves/SIMD, decorrelated barrier domains). H (8 bf16x8) lives in regs
// between phases. All ds_reads consumed by MFMAs before barriers. Math is
// instruction-identical to v6/v7 (bias C-init, chain order, gelu order).
// ---------------------------------------------------------------------------
__global__ __launch_bounds__(256, 2) void moe_main_kernel(
    const float* __restrict__ x, const float* __restrict__ gates,
    const __bf16* __restrict__ w1p, const __bf16* __restrict__ w2p,
    const float* __restrict__ be1p,
    const float* __restrict__ be2, const float* __restrict__ bs2,
    float* __restrict__ out)
{
    __shared__ __align__(16) char lds[65536];   // P: W1 @0 (32KB) | Q: W2 @32768

    const int t    = threadIdx.x;
    const int lane = t & 63;
    const int wv   = t >> 6;        // wave 0..3 = this wave's 32-token tile
    const int l31  = lane & 31;
    const int hi   = lane >> 5;
    const int tok0 = blockIdx.x * 128;
    const size_t row = (size_t)(tok0 + 32 * wv + l31);   // this lane's token

    // cooperative 32KB fill: wave wv copies its 8KB slice (8 x gl_lds16)
    #define FILL32K(dst, src)                                                   \
    {                                                                           \
        const char* g_ = (const char*)(src) + wv * 8192 + lane * 16;            \
        char* l_ = (dst) + wv * 8192;                                           \
        _Pragma("unroll")                                                       \
        for (int i_ = 0; i_ < 8; ++i_)                                          \
            gl_lds16(g_ + i_ * 1024, l_ + i_ * 1024);                           \
    }

    // prologue: fill P with W1(0)
    FILL32K(lds, w1p)

    // ---- X fragments in registers: xf[ks], k = 16ks + 8hi + j ----
    bf16x8 xf[8];
    {
        const float* xr = x + row * 128 + 8 * hi;
        #pragma unroll
        for (int ks = 0; ks < 8; ++ks) {
            f32x4 va = *(const f32x4*)(xr + 16 * ks);
            f32x4 vb = *(const f32x4*)(xr + 16 * ks + 4);
            bf16x8 v;
            v[0]=(__bf16)va[0]; v[1]=(__bf16)va[1]; v[2]=(__bf16)va[2]; v[3]=(__bf16)va[3];
            v[4]=(__bf16)vb[0]; v[5]=(__bf16)vb[1]; v[6]=(__bf16)vb[2]; v[7]=(__bf16)vb[3];
            xf[ks] = v;
        }
    }

    f32x16 acc0, acc1, acc2, acc3;
    #pragma unroll
    for (int i = 0; i < 16; ++i) { acc0[i]=0.f; acc1[i]=0.f; acc2[i]=0.f; acc3[i]=0.f; }

    const bf16x8* W1L = (const bf16x8*)(lds);            // P
    const bf16x8* W2L = (const bf16x8*)(lds + 32768);    // Q

    // prologue drain: W1(0) in P, all waves synced
    asm volatile("s_waitcnt vmcnt(0)" ::: "memory");
    __builtin_amdgcn_s_barrier();
    __builtin_amdgcn_sched_barrier(0);

    #pragma unroll 1
    for (int e = 0; e < 10; ++e) {
        // ================= G1 phase: GEMM1(P) + gelu -> H regs =============
        FILL32K(lds + 32768, (const char*)w2p + (size_t)e * 32768)   // Q <- W2(e)

        float gv = 1.0f;
        if (e < 8) gv = gates[row * 8 + e];
        f32x2 gv2; gv2[0] = gv; gv2[1] = gv;

        bf16x8 h[8];
        #pragma unroll
        for (int nt = 0; nt < 4; ++nt) {
            // W1 frags from P (contiguous 1KB wave-read: conflict-free)
            bf16x8 wb[8];
            #pragma unroll
            for (int ks = 0; ks < 8; ++ks) wb[ks] = W1L[(nt * 8 + ks) * 64 + lane];

            // bias frag (f32 exact, D-fragment order) = chain-0 C-init
            const f32x16 bfr = *(const f32x16*)(be1p + ((e * 4 + nt) * 2 + hi) * 16);

            __builtin_amdgcn_s_setprio(1);
            f32x16 alo = bfr;
            f32x16 ahi;
            #pragma unroll
            for (int i = 0; i < 16; ++i) ahi[i] = 0.f;
            #pragma unroll
            for (int ks = 0; ks < 4; ++ks) {
                alo = mfma32(wb[ks],     xf[ks],     alo);
                ahi = mfma32(wb[ks + 4], xf[ks + 4], ahi);
            }
            __builtin_amdgcn_s_setprio(0);

            f32x16 a = alo + ahi;
            h[2 * nt]     = gelu8p(a, 0, gv2);   // kq = 2nt
            h[2 * nt + 1] = gelu8p(a, 8, gv2);   // kq = 2nt+1
        }
        // Q fill had the whole G1 phase to land; drain + sync
        asm volatile("s_waitcnt vmcnt(0)" ::: "memory");
        __builtin_amdgcn_s_barrier();
        __builtin_amdgcn_sched_barrier(0);

        // ================= G2 phase: GEMM2(Q) ==============================
        if (e < 9) FILL32K(lds, (const char*)w1p + (size_t)(e + 1) * 32768)  // P <- W1(e+1)

        __builtin_amdgcn_s_setprio(1);
        #pragma unroll
        for (int kq = 0; kq < 8; ++kq) {
            bf16x8 wB0 = W2L[(kq * 4 + 0) * 64 + lane];
            bf16x8 wB1 = W2L[(kq * 4 + 1) * 64 + lane];
            bf16x8 wB2 = W2L[(kq * 4 + 2) * 64 + lane];
            bf16x8 wB3 = W2L[(kq * 4 + 3) * 64 + lane];
            acc0 = mfma32(h[kq], wB0, acc0);
            acc1 = mfma32(h[kq], wB1, acc1);
            acc2 = mfma32(h[kq], wB2, acc2);
            acc3 = mfma32(h[kq], wB3, acc3);
        }
        __builtin_amdgcn_s_setprio(0);

        // P fill drains here (partially covered by GEMM2; partner block
        // covers the remainder); sync before next G1 reads P
        asm volatile("s_waitcnt vmcnt(0)" ::: "memory");
        __builtin_amdgcn_s_barrier();
        __builtin_amdgcn_sched_barrier(0);
    }

    // ---- epilogue: bias (gate-weighted be2 + summed bs2) + store ----
    {
        float be2c[4][8], bsc[4];
        #pragma unroll
        for (int ot = 0; ot < 4; ++ot) {
            int o = 32 * ot + l31;
            bsc[ot] = bs2[o] + bs2[128 + o];
            #pragma unroll
            for (int ee = 0; ee < 8; ++ee) be2c[ot][ee] = be2[ee * 128 + o];
        }
        #pragma unroll
        for (int r = 0; r < 16; ++r) {
            int mrow = (r & 3) + 8 * (r >> 2) + 4 * hi;
            size_t trow = (size_t)(tok0 + 32 * wv + mrow);
            f32x4 g0 = *(const f32x4*)(gates + trow * 8);
            f32x4 g1 = *(const f32x4*)(gates + trow * 8 + 4);
            size_t obase = trow * 128 + l31;
            #pragma unroll
            for (int ot = 0; ot < 4; ++ot) {
                float b = bsc[ot];
                #pragma unroll
                for (int ee = 0; ee < 4; ++ee) b = fmaf(g0[ee], be2c[ot][ee], b);
                #pragma unroll
                for (int ee = 0; ee < 4; ++ee) b = fmaf(g1[ee], be2c[ot][4 + ee], b);
                float av = (ot == 0) ? acc0[r] : (ot == 1) ? acc1[r]
                         : (ot == 2) ? acc2[r] : acc3[r];
                out[obase + 32 * ot] = av + b;
            }
        }
    }
    #undef FILL32K
}

// ---------------------------------------------------------------------------
extern "C" void kernel_launch(void* const* d_in, const int* in_sizes, int n_in,
                              void* d_out, int out_size, void* d_ws, size_t ws_size,
                              hipStream_t stream)
{
    const float* x   = (const float*)d_in[0];
    const float* Wr1 = (const float*)d_in[1];
    const float* br1 = (const float*)d_in[2];
    const float* Wr2 = (const float*)d_in[3];
    const float* br2 = (const float*)d_in[4];
    const float* We1 = (const float*)d_in[5];
    const float* be1 = (const float*)d_in[6];
    const float* We2 = (const float*)d_in[7];
    const float* be2 = (const float*)d_in[8];
    const float* Ws1 = (const float*)d_in[9];
    const float* bs1 = (const float*)d_in[10];
    const float* Ws2 = (const float*)d_in[11];
    const float* bs2 = (const float*)d_in[12];

    // ws: w1p [0,327680); w2p [327680,655360); be1p [655360,660480);
    // wr1d [660480,676864); wr2d [676864,677888); br1d [677888,678016);
    // br2d [678016,678080); gates [720896, 720896+2097152)
    __bf16* w1p  = (__bf16*)d_ws;
    __bf16* w2p  = (__bf16*)((char*)d_ws + 327680);
    float*  be1p = (float*)((char*)d_ws + 655360);
    double* wr1d = (double*)((char*)d_ws + 660480);
    double* wr2d = (double*)((char*)d_ws + 676864);
    double* br1d = (double*)((char*)d_ws + 677888);
    double* br2d = (double*)((char*)d_ws + 678016);
    float*  gts  = (float*)((char*)d_ws + 720896);

    pack_kernel<<<174, 256, 0, stream>>>(We1, be1, Ws1, bs1, We2, Ws2,
                                         Wr1, br1, Wr2, br2,
                                         w1p, w2p, be1p, wr1d, br1d, wr2d, br2d);
    router_kernel<<<1024, 256, 0, stream>>>(x, wr1d, br1d, wr2d, br2d, gts);
    moe_main_kernel<<<512, 256, 0, stream>>>(x, gts, w1p, w2p, be1p, be2, bs2,
                                             (float*)d_out);
}